// Round 7
// baseline (68.961 us; speedup 1.0000x reference)
//
#include <hip/hip_runtime.h>

// Problem constants
#define NQ 20
#define DIMQ (1 << NQ)          // 2^20
#define NB 16                   // BATCH
#define NT 4                    // N_TERMS
#define RBITS 15                // low bits untouched by gates
#define NCOL (1 << (RBITS + 4)) // 2^15 r-values * 16 batches = 524288 columns

// U table layout in ws: per (k,b): 32 floats (16 complex interleaved)
//   base = (k*16 + b) * 32 ; entry (i,j): re at base + (i*4+j)*2, im at +1
#define USTRIDE 32
#define UTOT (64 * USTRIDE)     // 2048 floats = 8 KiB

// ---------------------------------------------------------------------------
// Kernel A: U[k,b] = exp(-i * H_k * t_{k,b}),  H_k = 0.5*(A + A^H), A = Hr + i Hi
// 256 threads: 64 tasks (k,b) x 4 rows. Scaling (2^-6) + 10-term Taylor + 6 squarings.
// ---------------------------------------------------------------------------
__global__ __launch_bounds__(256) void compute_u_kernel(
    const float* __restrict__ Hre, const float* __restrict__ Him,
    const float* __restrict__ tevo, float* __restrict__ uout) {
  __shared__ float er_s[64][4][4];
  __shared__ float ei_s[64][4][4];

  const int tid  = threadIdx.x;   // 0..255
  const int task = tid >> 2;      // 0..63
  const int row  = tid & 3;       // 0..3
  const int k    = task >> 4;     // 0..3
  const int b    = task & 15;     // 0..15

  float Ar[4][4], Ai[4][4];
#pragma unroll
  for (int i = 0; i < 4; i++) {
#pragma unroll
    for (int j = 0; j < 4; j++) {
      Ar[i][j] = Hre[k * 16 + i * 4 + j];
      Ai[i][j] = Him[k * 16 + i * 4 + j];
    }
  }
  const float t = tevo[k * NB + b];
  const float ts = t * (1.0f / 64.0f);  // scale 2^-6 folded in

  // G = -i * H * ts ; H = 0.5*(A + A^H)
  float Gr[4][4], Gi[4][4];
#pragma unroll
  for (int i = 0; i < 4; i++) {
#pragma unroll
    for (int j = 0; j < 4; j++) {
      const float hr = 0.5f * (Ar[i][j] + Ar[j][i]);
      const float hi = 0.5f * (Ai[i][j] - Ai[j][i]);
      Gr[i][j] = ts * hi;
      Gi[i][j] = -ts * hr;
    }
  }

  // Taylor: E = I + sum_{m=1..10} G^m/m!   (row `row` only; full G in regs)
  float Er[4], Ei[4], Tr[4], Ti[4];
#pragma unroll
  for (int j = 0; j < 4; j++) {
    Er[j] = (j == row) ? 1.0f : 0.0f;
    Ei[j] = 0.0f;
    Tr[j] = Er[j];
    Ti[j] = 0.0f;
  }
#pragma unroll
  for (int m = 1; m <= 10; m++) {
    const float inv = 1.0f / (float)m;
    float nr[4], ni[4];
#pragma unroll
    for (int j = 0; j < 4; j++) {
      float ar = 0.0f, ai = 0.0f;
#pragma unroll
      for (int p = 0; p < 4; p++) {
        ar += Tr[p] * Gr[p][j] - Ti[p] * Gi[p][j];
        ai += Tr[p] * Gi[p][j] + Ti[p] * Gr[p][j];
      }
      nr[j] = ar * inv;
      ni[j] = ai * inv;
    }
#pragma unroll
    for (int j = 0; j < 4; j++) {
      Tr[j] = nr[j]; Ti[j] = ni[j];
      Er[j] += nr[j]; Ei[j] += ni[j];
    }
  }

  // 6 squarings via LDS (uniform trip count -> barriers are safe)
  for (int q = 0; q < 6; q++) {
    __syncthreads();
#pragma unroll
    for (int j = 0; j < 4; j++) {
      er_s[task][row][j] = Er[j];
      ei_s[task][row][j] = Ei[j];
    }
    __syncthreads();
    float nr[4], ni[4];
#pragma unroll
    for (int j = 0; j < 4; j++) {
      float ar = 0.0f, ai = 0.0f;
#pragma unroll
      for (int p = 0; p < 4; p++) {
        ar += Er[p] * er_s[task][p][j] - Ei[p] * ei_s[task][p][j];
        ai += Er[p] * ei_s[task][p][j] + Ei[p] * er_s[task][p][j];
      }
      nr[j] = ar; ni[j] = ai;
    }
#pragma unroll
    for (int j = 0; j < 4; j++) { Er[j] = nr[j]; Ei[j] = ni[j]; }
  }

  // Store U rows: layout [k][b][16 complex interleaved], row stride 32 floats
  const int ubase = (k * 16 + b) * USTRIDE;
#pragma unroll
  for (int j = 0; j < 4; j++) {
    uout[ubase + (row * 4 + j) * 2]     = Er[j];
    uout[ubase + (row * 4 + j) * 2 + 1] = Ei[j];
  }
}

// ---------------------------------------------------------------------------
// Kernel B: FOUR lanes per column (r,b); lane owns quadrant q = tid&3 of the
// 32-g group (8 amplitudes: g = q*8 + m). col = blockIdx*64 + (tid>>2).
//   k=2,3: g bits [2:1],[1:0] -> pure in-thread.
//   k=1:   g bits [3:2] -> bit3 = q0: partner lane^1, one 8-complex shfl set.
//   k=0:   g bits [4:3] = q     -> 3 rotation steps shfl_xor(d), d=1..3,
//          U0 entry [q][q^d] loaded per-lane as float2 (runtime-q ADDRESS
//          arithmetic, never register indexing).
// Per-thread live set ~50 floats -> genuinely fits the compiler's ~64-VGPR
// comfort zone: the 16-load burst stays resident, no fold-into-use, no spill.
// Every state element read exactly once; U read straight from global (L1-hot).
// ---------------------------------------------------------------------------
__global__ __launch_bounds__(256, 4) void apply_gates_kernel(
    const float* __restrict__ sre, const float* __restrict__ sim,
    const float* __restrict__ u, float* __restrict__ out) {
  const int tid = threadIdx.x;
  const int q   = tid & 3;                       // owned quadrant = g bits [4:3]
  const int q0  = q & 1;                         // g bit 3
  const int col = blockIdx.x * 64 + (tid >> 2);  // r*16 + b
  const int b   = (tid >> 2) & 15;

  // own 8 amplitudes: g = q*8 + m  (one burst of 16 dword loads)
  float s_re[8], s_im[8];
#pragma unroll
  for (int m = 0; m < 8; m++) {
    const int off = col + ((q * 8 + m) << 19);
    s_re[m] = sre[off];
    s_im[m] = sim[off];
  }

  float o_re[8], o_im[8];

  // ---- k = 3 (g bits [1:0]) : in-thread; initializes acc ----
  // out[l2*4+i] = sum_j U3[i][j] * s[l2*4+j]
  {
    const float* ub = &u[(3 * 16 + b) * USTRIDE];
#pragma unroll
    for (int i = 0; i < 4; i++) {
      const float4 v0 = *(const float4*)(ub + i * 8);      // entries j=0,1
      const float4 v1 = *(const float4*)(ub + i * 8 + 4);  // entries j=2,3
#pragma unroll
      for (int l2 = 0; l2 < 2; l2++) {
        const int o = l2 * 4 + i;
        const int a = l2 * 4;
        o_re[o] = v0.x * s_re[a]     - v0.y * s_im[a]
                + v0.z * s_re[a + 1] - v0.w * s_im[a + 1]
                + v1.x * s_re[a + 2] - v1.y * s_im[a + 2]
                + v1.z * s_re[a + 3] - v1.w * s_im[a + 3];
        o_im[o] = v0.x * s_im[a]     + v0.y * s_re[a]
                + v0.z * s_im[a + 1] + v0.w * s_re[a + 1]
                + v1.x * s_im[a + 2] + v1.y * s_re[a + 2]
                + v1.z * s_im[a + 3] + v1.w * s_re[a + 3];
      }
    }
  }

  // ---- k = 2 (g bits [2:1]) : in-thread ----
  // out[i*2+l0] += sum_j U2[i][j] * s[j*2+l0]
  {
    const float* ub = &u[(2 * 16 + b) * USTRIDE];
#pragma unroll
    for (int i = 0; i < 4; i++) {
      const float4 v0 = *(const float4*)(ub + i * 8);
      const float4 v1 = *(const float4*)(ub + i * 8 + 4);
#pragma unroll
      for (int l0 = 0; l0 < 2; l0++) {
        const int o = i * 2 + l0;
        o_re[o] += v0.x * s_re[l0]     - v0.y * s_im[l0]
                 + v0.z * s_re[2 + l0] - v0.w * s_im[2 + l0]
                 + v1.x * s_re[4 + l0] - v1.y * s_im[4 + l0]
                 + v1.z * s_re[6 + l0] - v1.w * s_im[6 + l0];
        o_im[o] += v0.x * s_im[l0]     + v0.y * s_re[l0]
                 + v0.z * s_im[2 + l0] + v0.w * s_re[2 + l0]
                 + v1.x * s_im[4 + l0] + v1.y * s_re[4 + l0]
                 + v1.z * s_im[6 + l0] + v1.w * s_re[6 + l0];
      }
    }
  }

  // ---- k = 1 (g bits [3:2]) : partner = lane^1 (flips q0 = g bit 3) ----
  // out[l2*4+ll] += sum_{j3,j2} U1[q0*2+l2][j3*2+j2] * src(j3)[j2*4+ll]
  {
    const float* ub = &u[(1 * 16 + b) * USTRIDE];
    float t_re[8], t_im[8];
#pragma unroll
    for (int m = 0; m < 8; m++) {
      t_re[m] = __shfl_xor(s_re[m], 1, 64);
      t_im[m] = __shfl_xor(s_im[m], 1, 64);
    }
#pragma unroll
    for (int l2 = 0; l2 < 2; l2++) {
      const float* row = ub + (q0 * 2 + l2) * 8;
      const float2 co0 = *(const float2*)(row + (q0 * 2 + 0) * 2);        // own j2=0
      const float2 co1 = *(const float2*)(row + (q0 * 2 + 1) * 2);        // own j2=1
      const float2 cp0 = *(const float2*)(row + ((q0 ^ 1) * 2 + 0) * 2);  // partner j2=0
      const float2 cp1 = *(const float2*)(row + ((q0 ^ 1) * 2 + 1) * 2);  // partner j2=1
#pragma unroll
      for (int ll = 0; ll < 4; ll++) {
        const int o = l2 * 4 + ll;
        o_re[o] += co0.x * s_re[ll]     - co0.y * s_im[ll]
                 + co1.x * s_re[4 + ll] - co1.y * s_im[4 + ll]
                 + cp0.x * t_re[ll]     - cp0.y * t_im[ll]
                 + cp1.x * t_re[4 + ll] - cp1.y * t_im[4 + ll];
        o_im[o] += co0.x * s_im[ll]     + co0.y * s_re[ll]
                 + co1.x * s_im[4 + ll] + co1.y * s_re[4 + ll]
                 + cp0.x * t_im[ll]     + cp0.y * t_re[ll]
                 + cp1.x * t_im[4 + ll] + cp1.y * t_re[4 + ll];
      }
    }
  }

  // ---- k = 0 (g bits [4:3] = q) : rotation over d, U0 entry [q][q^d] ----
  {
    const float* ub = &u[(0 * 16 + b) * USTRIDE];
    const float2 c0 = *(const float2*)(ub + q * 8 + q * 2);  // d=0: own
#pragma unroll
    for (int m = 0; m < 8; m++) {
      o_re[m] += c0.x * s_re[m] - c0.y * s_im[m];
      o_im[m] += c0.x * s_im[m] + c0.y * s_re[m];
    }
#pragma unroll
    for (int d = 1; d < 4; d++) {
      const float2 cd = *(const float2*)(ub + q * 8 + (q ^ d) * 2);
#pragma unroll
      for (int m = 0; m < 8; m++) {
        const float tr = __shfl_xor(s_re[m], d, 64);
        const float ti = __shfl_xor(s_im[m], d, 64);
        o_re[m] += cd.x * tr - cd.y * ti;
        o_im[m] += cd.x * ti + cd.y * tr;
      }
    }
  }

#pragma unroll
  for (int m = 0; m < 8; m++) {
    const int off = col + ((q * 8 + m) << 19);
    __builtin_nontemporal_store(o_re[m], out + off);               // real
    __builtin_nontemporal_store(o_im[m], out + off + (1 << 24));   // imag
  }
}

extern "C" void kernel_launch(void* const* d_in, const int* in_sizes, int n_in,
                              void* d_out, int out_size, void* d_ws, size_t ws_size,
                              hipStream_t stream) {
  const float* Hre  = (const float*)d_in[0];
  const float* Him  = (const float*)d_in[1];
  const float* tevo = (const float*)d_in[2];
  const float* sre  = (const float*)d_in[3];
  const float* sim  = (const float*)d_in[4];
  float* out = (float*)d_out;
  float* uws = (float*)d_ws;  // UTOT floats = 8 KiB

  compute_u_kernel<<<1, 256, 0, stream>>>(Hre, Him, tevo, uws);
  apply_gates_kernel<<<NCOL / 64, 256, 0, stream>>>(sre, sim, uws, out);
}

// Round 8
// 68.852 us; speedup vs baseline: 1.0016x; 1.0016x over previous
//
#include <hip/hip_runtime.h>

// Problem constants
#define NQ 20
#define DIMQ (1 << NQ)          // 2^20
#define NB 16                   // BATCH
#define NT 4                    // N_TERMS
#define RBITS 15                // low bits untouched by gates
#define NCOL (1 << (RBITS + 4)) // 2^15 r-values * 16 batches = 524288 columns

// U table layout in ws: per (k,b): 32 floats (16 complex interleaved)
//   base = (k*16 + b) * 32 ; entry (i,j): re at base + (i*4+j)*2, im at +1
//   128 B per (k,b) -> cache-line aligned.
#define USTRIDE 32
#define UTOT (64 * USTRIDE)     // 2048 floats = 8 KiB

// ---------------------------------------------------------------------------
// Kernel A: U[k,b] = exp(-i * H_k * t_{k,b}),  H_k = 0.5*(A + A^H), A = Hr + i Hi
// 256 threads: 64 tasks (k,b) x 4 rows. Scaling (2^-6) + 10-term Taylor + 6 squarings.
// ---------------------------------------------------------------------------
__global__ __launch_bounds__(256) void compute_u_kernel(
    const float* __restrict__ Hre, const float* __restrict__ Him,
    const float* __restrict__ tevo, float* __restrict__ uout) {
  __shared__ float er_s[64][4][4];
  __shared__ float ei_s[64][4][4];

  const int tid  = threadIdx.x;   // 0..255
  const int task = tid >> 2;      // 0..63
  const int row  = tid & 3;       // 0..3
  const int k    = task >> 4;     // 0..3
  const int b    = task & 15;     // 0..15

  float Ar[4][4], Ai[4][4];
#pragma unroll
  for (int i = 0; i < 4; i++) {
#pragma unroll
    for (int j = 0; j < 4; j++) {
      Ar[i][j] = Hre[k * 16 + i * 4 + j];
      Ai[i][j] = Him[k * 16 + i * 4 + j];
    }
  }
  const float t = tevo[k * NB + b];
  const float ts = t * (1.0f / 64.0f);  // scale 2^-6 folded in

  // G = -i * H * ts ; H = 0.5*(A + A^H)
  float Gr[4][4], Gi[4][4];
#pragma unroll
  for (int i = 0; i < 4; i++) {
#pragma unroll
    for (int j = 0; j < 4; j++) {
      const float hr = 0.5f * (Ar[i][j] + Ar[j][i]);
      const float hi = 0.5f * (Ai[i][j] - Ai[j][i]);
      Gr[i][j] = ts * hi;
      Gi[i][j] = -ts * hr;
    }
  }

  // Taylor: E = I + sum_{m=1..10} G^m/m!   (row `row` only; full G in regs)
  float Er[4], Ei[4], Tr[4], Ti[4];
#pragma unroll
  for (int j = 0; j < 4; j++) {
    Er[j] = (j == row) ? 1.0f : 0.0f;
    Ei[j] = 0.0f;
    Tr[j] = Er[j];
    Ti[j] = 0.0f;
  }
#pragma unroll
  for (int m = 1; m <= 10; m++) {
    const float inv = 1.0f / (float)m;
    float nr[4], ni[4];
#pragma unroll
    for (int j = 0; j < 4; j++) {
      float ar = 0.0f, ai = 0.0f;
#pragma unroll
      for (int p = 0; p < 4; p++) {
        ar += Tr[p] * Gr[p][j] - Ti[p] * Gi[p][j];
        ai += Tr[p] * Gi[p][j] + Ti[p] * Gr[p][j];
      }
      nr[j] = ar * inv;
      ni[j] = ai * inv;
    }
#pragma unroll
    for (int j = 0; j < 4; j++) {
      Tr[j] = nr[j]; Ti[j] = ni[j];
      Er[j] += nr[j]; Ei[j] += ni[j];
    }
  }

  // 6 squarings via LDS (uniform trip count -> barriers are safe)
  for (int q = 0; q < 6; q++) {
    __syncthreads();
#pragma unroll
    for (int j = 0; j < 4; j++) {
      er_s[task][row][j] = Er[j];
      ei_s[task][row][j] = Ei[j];
    }
    __syncthreads();
    float nr[4], ni[4];
#pragma unroll
    for (int j = 0; j < 4; j++) {
      float ar = 0.0f, ai = 0.0f;
#pragma unroll
      for (int p = 0; p < 4; p++) {
        ar += Er[p] * er_s[task][p][j] - Ei[p] * ei_s[task][p][j];
        ai += Er[p] * ei_s[task][p][j] + Ei[p] * er_s[task][p][j];
      }
      nr[j] = ar; ni[j] = ai;
    }
#pragma unroll
    for (int j = 0; j < 4; j++) { Er[j] = nr[j]; Ei[j] = ni[j]; }
  }

  // Store U rows: layout [k][b][16 complex interleaved], row stride 32 floats
  const int ubase = (k * 16 + b) * USTRIDE;
#pragma unroll
  for (int j = 0; j < 4; j++) {
    uout[ubase + (row * 4 + j) * 2]     = Er[j];
    uout[ubase + (row * 4 + j) * 2 + 1] = Ei[j];
  }
}

// ---------------------------------------------------------------------------
// Kernel B (r5 structure, latency-tuned): two ADJACENT LANES per column
// (r,b); each owns one 16-g half. half = tid&1, col = blockIdx*128+(tid>>1).
//   k=1..3: local to the half (g bits [3:0]) — computed FIRST (k=1 inits the
//           accumulator) so FMAs start as soon as early state loads land.
//   k=0:    cross-half (g bits [4:3]) — own term + partner partial exchanged
//           via __shfl_xor(.,1), done LAST so the ds_bpermute latency
//           overlaps the k1..3 tail.
// No LDS/barrier: 8 KiB U table read straight from global (L1-hot,
// broadcast). No asm pinning (r6 lesson: it forces scratch). Plain cached
// state loads (L3 reuse across replays), NT stores (output never re-read).
// ---------------------------------------------------------------------------
__global__ __launch_bounds__(256) void apply_gates_kernel(
    const float* __restrict__ sre, const float* __restrict__ sim,
    const float* __restrict__ u, float* __restrict__ out) {
  const int tid   = threadIdx.x;
  const int half  = tid & 1;                        // lanes alternate halves
  const int col   = blockIdx.x * 128 + (tid >> 1);  // r*16 + b
  const int b     = (tid >> 1) & 15;
  const int gbase = half << 4;

  // own half: 16 complex, one burst of 32 dword loads
  float s_re[16], s_im[16];
#pragma unroll
  for (int q = 0; q < 16; q++) {
    const int off = col + ((gbase + q) << 19);
    s_re[q] = sre[off];
    s_im[q] = sim[off];
  }

  float o_re[16], o_im[16];

  // ---- k = 1 (sh=2): local; INITIALIZES the accumulator ----
  {
    const int sh = 2;
    const float* ub = &u[(1 * 16 + b) * USTRIDE];
#pragma unroll
    for (int i = 0; i < 4; i++) {
      const float4 v0 = *(const float4*)(ub + i * 8);      // j=0,1
      const float4 v1 = *(const float4*)(ub + i * 8 + 4);  // j=2,3
#pragma unroll
      for (int qq = 0; qq < 4; qq++) {
        const int low  = qq & ((1 << sh) - 1);
        const int high = (qq >> sh) << (sh + 2);
        const int gb   = high | low;
        const int gq   = gb | (i << sh);
        const int s0 = gb;
        const int s1 = gb | (1 << sh);
        const int s2 = gb | (2 << sh);
        const int s3 = gb | (3 << sh);
        o_re[gq] = v0.x * s_re[s0] - v0.y * s_im[s0]
                 + v0.z * s_re[s1] - v0.w * s_im[s1]
                 + v1.x * s_re[s2] - v1.y * s_im[s2]
                 + v1.z * s_re[s3] - v1.w * s_im[s3];
        o_im[gq] = v0.x * s_im[s0] + v0.y * s_re[s0]
                 + v0.z * s_im[s1] + v0.w * s_re[s1]
                 + v1.x * s_im[s2] + v1.y * s_re[s2]
                 + v1.z * s_im[s3] + v1.w * s_re[s3];
      }
    }
  }

  // ---- k = 2..3: local, accumulate ----
#pragma unroll
  for (int k = 2; k < 4; k++) {
    const int sh = 3 - k;  // 1, 0
    const float* ub = &u[(k * 16 + b) * USTRIDE];
#pragma unroll
    for (int i = 0; i < 4; i++) {
      const float4 v0 = *(const float4*)(ub + i * 8);      // j=0,1
      const float4 v1 = *(const float4*)(ub + i * 8 + 4);  // j=2,3
#pragma unroll
      for (int qq = 0; qq < 4; qq++) {
        const int low  = qq & ((1 << sh) - 1);
        const int high = (qq >> sh) << (sh + 2);
        const int gb   = high | low;
        const int gq   = gb | (i << sh);
        const int s0 = gb;
        const int s1 = gb | (1 << sh);
        const int s2 = gb | (2 << sh);
        const int s3 = gb | (3 << sh);
        o_re[gq] += v0.x * s_re[s0] - v0.y * s_im[s0]
                  + v0.z * s_re[s1] - v0.w * s_im[s1]
                  + v1.x * s_re[s2] - v1.y * s_im[s2]
                  + v1.z * s_re[s3] - v1.w * s_im[s3];
        o_im[gq] += v0.x * s_im[s0] + v0.y * s_re[s0]
                  + v0.z * s_im[s1] + v0.w * s_re[s1]
                  + v1.x * s_im[s2] + v1.y * s_re[s2]
                  + v1.z * s_im[s3] + v1.w * s_re[s3];
      }
    }
  }

  // ---- k = 0 (g bits [4:3]) : own term + shfl-exchanged cross term, LAST ----
  // own output g = half<<4 | b3<<3 | l : U row i = 2*half + b3;
  // own sources s[l] (j=2*half), s[8+l] (j=2*half+1).
  // cross partial: my sources' contribution to partner's output (row
  // i' = 2*(half^1) + b3); partner adds the swapped value.
  {
    const float* ub0 = &u[b * USTRIDE];  // k = 0 block
    const int h4 = half * 4;             // float offset of (j=2h) entry pair
#pragma unroll
    for (int b3 = 0; b3 < 2; b3++) {
      const float4 vo = *(const float4*)(ub0 + (half * 2 + b3) * 8 + h4);
      const float4 vc = *(const float4*)(ub0 + ((half ^ 1) * 2 + b3) * 8 + h4);
#pragma unroll
      for (int l = 0; l < 8; l++) {
        const int gq = b3 * 8 + l;
        float pr = vc.x * s_re[l]     - vc.y * s_im[l]
                 + vc.z * s_re[8 + l] - vc.w * s_im[8 + l];
        float pi = vc.x * s_im[l]     + vc.y * s_re[l]
                 + vc.z * s_im[8 + l] + vc.w * s_re[8 + l];
        o_re[gq] += vo.x * s_re[l]     - vo.y * s_im[l]
                  + vo.z * s_re[8 + l] - vo.w * s_im[8 + l]
                  + __shfl_xor(pr, 1, 64);
        o_im[gq] += vo.x * s_im[l]     + vo.y * s_re[l]
                  + vo.z * s_im[8 + l] + vo.w * s_re[8 + l]
                  + __shfl_xor(pi, 1, 64);
      }
    }
  }

#pragma unroll
  for (int q = 0; q < 16; q++) {
    const int off = col + ((gbase + q) << 19);
    __builtin_nontemporal_store(o_re[q], out + off);               // real
    __builtin_nontemporal_store(o_im[q], out + off + (1 << 24));   // imag
  }
}

extern "C" void kernel_launch(void* const* d_in, const int* in_sizes, int n_in,
                              void* d_out, int out_size, void* d_ws, size_t ws_size,
                              hipStream_t stream) {
  const float* Hre  = (const float*)d_in[0];
  const float* Him  = (const float*)d_in[1];
  const float* tevo = (const float*)d_in[2];
  const float* sre  = (const float*)d_in[3];
  const float* sim  = (const float*)d_in[4];
  float* out = (float*)d_out;
  float* uws = (float*)d_ws;  // UTOT floats = 8 KiB

  compute_u_kernel<<<1, 256, 0, stream>>>(Hre, Him, tevo, uws);
  apply_gates_kernel<<<NCOL / 128, 256, 0, stream>>>(sre, sim, uws, out);
}

// Round 9
// 64.792 us; speedup vs baseline: 1.0643x; 1.0627x over previous
//
#include <hip/hip_runtime.h>

// Problem constants
#define NQ 20
#define DIMQ (1 << NQ)          // 2^20
#define NB 16                   // BATCH
#define NT 4                    // N_TERMS
#define RBITS 15                // low bits untouched by gates
#define NCOL (1 << (RBITS + 4)) // 2^15 r-values * 16 batches = 524288 columns

// U table layout in ws/LDS: per (k,b): 36 floats (16 complex interleaved + 4 pad)
//   base = (k*16 + b) * 36 ; entry (i,j): re at base + (i*4+j)*2, im at +1
//   stride 36 floats -> bank = 4b%32: 2-way aliasing only (free per m136).
#define USTRIDE 36
#define UTOT (64 * USTRIDE)     // 2304 floats = 9216 B = 9*256 floats

// ---------------------------------------------------------------------------
// Kernel A: U[k,b] = exp(-i * H_k * t_{k,b}),  H_k = 0.5*(A + A^H), A = Hr + i Hi
// 256 threads: 64 tasks (k,b) x 4 rows. Scaling (2^-6) + 10-term Taylor + 6 squarings.
// ---------------------------------------------------------------------------
__global__ __launch_bounds__(256) void compute_u_kernel(
    const float* __restrict__ Hre, const float* __restrict__ Him,
    const float* __restrict__ tevo, float* __restrict__ uout) {
  __shared__ float er_s[64][4][4];
  __shared__ float ei_s[64][4][4];

  const int tid  = threadIdx.x;   // 0..255
  const int task = tid >> 2;      // 0..63
  const int row  = tid & 3;       // 0..3
  const int k    = task >> 4;     // 0..3
  const int b    = task & 15;     // 0..15

  float Ar[4][4], Ai[4][4];
#pragma unroll
  for (int i = 0; i < 4; i++) {
#pragma unroll
    for (int j = 0; j < 4; j++) {
      Ar[i][j] = Hre[k * 16 + i * 4 + j];
      Ai[i][j] = Him[k * 16 + i * 4 + j];
    }
  }
  const float t = tevo[k * NB + b];
  const float ts = t * (1.0f / 64.0f);  // scale 2^-6 folded in

  // G = -i * H * ts ; H = 0.5*(A + A^H)
  float Gr[4][4], Gi[4][4];
#pragma unroll
  for (int i = 0; i < 4; i++) {
#pragma unroll
    for (int j = 0; j < 4; j++) {
      const float hr = 0.5f * (Ar[i][j] + Ar[j][i]);
      const float hi = 0.5f * (Ai[i][j] - Ai[j][i]);
      Gr[i][j] = ts * hi;
      Gi[i][j] = -ts * hr;
    }
  }

  // Taylor: E = I + sum_{m=1..10} G^m/m!   (row `row` only; full G in regs)
  float Er[4], Ei[4], Tr[4], Ti[4];
#pragma unroll
  for (int j = 0; j < 4; j++) {
    Er[j] = (j == row) ? 1.0f : 0.0f;
    Ei[j] = 0.0f;
    Tr[j] = Er[j];
    Ti[j] = 0.0f;
  }
#pragma unroll
  for (int m = 1; m <= 10; m++) {
    const float inv = 1.0f / (float)m;
    float nr[4], ni[4];
#pragma unroll
    for (int j = 0; j < 4; j++) {
      float ar = 0.0f, ai = 0.0f;
#pragma unroll
      for (int p = 0; p < 4; p++) {
        ar += Tr[p] * Gr[p][j] - Ti[p] * Gi[p][j];
        ai += Tr[p] * Gi[p][j] + Ti[p] * Gr[p][j];
      }
      nr[j] = ar * inv;
      ni[j] = ai * inv;
    }
#pragma unroll
    for (int j = 0; j < 4; j++) {
      Tr[j] = nr[j]; Ti[j] = ni[j];
      Er[j] += nr[j]; Ei[j] += ni[j];
    }
  }

  // 6 squarings via LDS (uniform trip count -> barriers are safe)
  for (int q = 0; q < 6; q++) {
    __syncthreads();
#pragma unroll
    for (int j = 0; j < 4; j++) {
      er_s[task][row][j] = Er[j];
      ei_s[task][row][j] = Ei[j];
    }
    __syncthreads();
    float nr[4], ni[4];
#pragma unroll
    for (int j = 0; j < 4; j++) {
      float ar = 0.0f, ai = 0.0f;
#pragma unroll
      for (int p = 0; p < 4; p++) {
        ar += Er[p] * er_s[task][p][j] - Ei[p] * ei_s[task][p][j];
        ai += Er[p] * ei_s[task][p][j] + Ei[p] * er_s[task][p][j];
      }
      nr[j] = ar; ni[j] = ai;
    }
#pragma unroll
    for (int j = 0; j < 4; j++) { Er[j] = nr[j]; Ei[j] = ni[j]; }
  }

  // Store U rows: layout [k][b][16 complex interleaved], row stride 36 floats
  const int ubase = (k * 16 + b) * USTRIDE;
#pragma unroll
  for (int j = 0; j < 4; j++) {
    uout[ubase + (row * 4 + j) * 2]     = Er[j];
    uout[ubase + (row * 4 + j) * 2 + 1] = Ei[j];
  }
}

// ---------------------------------------------------------------------------
// Kernel B (r5 compute core + DMA-staged state):
// Block = 128 columns. State tile [g][col] (32 x 128 floats per re/im, 32 KB)
// staged via global_load_lds width-16: LDS dest is linear lane*16B (the DMA
// requirement), source per-lane = row-pair layout. Zero VGPR cost, deep queue.
// Then 2 lanes per column (half = tid&1) read their 16 complex from LDS
// (ds_read_b32, 2-way bank aliasing = free) -> fold-into-use at LDS latency
// (~120cy) instead of HBM (~900cy), which was r5's residual stall.
// U table in LDS (stride 36), k=0 cross-half via __shfl_xor as r5.
// ---------------------------------------------------------------------------
__global__ __launch_bounds__(256, 4) void apply_gates_kernel(
    const float* __restrict__ sre, const float* __restrict__ sim,
    const float* __restrict__ u, float* __restrict__ out) {
  __shared__ __align__(16) float ul[UTOT];        // 9216 B
  __shared__ __align__(16) float slr[32 * 128];   // 16 KB  re tile [g][col]
  __shared__ __align__(16) float sli[32 * 128];   // 16 KB  im tile [g][col]

  const int tid = threadIdx.x;
  const int c0  = blockIdx.x * 128;   // column base (r*16+b units)

  // ---- DMA the state tile: 32 instrs/block (8 per wave), 1 KB each ----
  // instr p (0..31): p<16 -> re row-pair p, else im row-pair p-16.
  // lane l: row = 2*pr + (l>>5), cols (l&31)*4 .. +3 ; LDS dest pr*256 floats.
  {
    const int w = tid >> 6;
    const int l = tid & 63;
#pragma unroll
    for (int t = 0; t < 8; t++) {
      const int p   = t * 4 + w;       // 0..31
      const int pr  = p & 15;
      const int row = 2 * pr + (l >> 5);
      const int cc  = (l & 31) * 4;
      const float* src = (p < 16 ? sre : sim) + (row << 19) + c0 + cc;
      float* dst = (p < 16 ? slr : sli) + pr * 256;  // wave-uniform base
      __builtin_amdgcn_global_load_lds(
          (const __attribute__((address_space(1))) float*)(const void*)src,
          (__attribute__((address_space(3))) float*)(void*)dst, 16, 0, 0);
    }
  }

  // ---- stage U table (9 KiB) to LDS; UTOT = 9*256 exactly ----
#pragma unroll
  for (int q = 0; q < 9; q++) ul[tid + q * 256] = u[tid + q * 256];
  __syncthreads();   // drains DMA (vmcnt) + U writes (lgkmcnt)

  const int half  = tid & 1;          // lanes alternate halves
  const int cidx  = tid >> 1;         // 0..127
  const int col   = c0 + cidx;        // r*16 + b
  const int b     = cidx & 15;
  const int gbase = half << 4;

  // own half: 16 complex from LDS (2-way bank aliasing only)
  float s_re[16], s_im[16];
#pragma unroll
  for (int q = 0; q < 16; q++) {
    s_re[q] = slr[(gbase + q) * 128 + cidx];
    s_im[q] = sli[(gbase + q) * 128 + cidx];
  }

  float o_re[16], o_im[16];

  // ---- k = 0 (g bits [4:3]) : own term + shfl-exchanged cross term ----
  {
    const float* ub0 = &ul[b * USTRIDE];  // k = 0 block
    const int h4 = half * 4;              // float offset of (j=2h) entry pair
#pragma unroll
    for (int b3 = 0; b3 < 2; b3++) {
      const float4 vo = *(const float4*)(ub0 + (half * 2 + b3) * 8 + h4);
      const float4 vc = *(const float4*)(ub0 + ((half ^ 1) * 2 + b3) * 8 + h4);
#pragma unroll
      for (int l = 0; l < 8; l++) {
        const int gq = b3 * 8 + l;
        o_re[gq] = vo.x * s_re[l]     - vo.y * s_im[l]
                 + vo.z * s_re[8 + l] - vo.w * s_im[8 + l];
        o_im[gq] = vo.x * s_im[l]     + vo.y * s_re[l]
                 + vo.z * s_im[8 + l] + vo.w * s_re[8 + l];
        float pr = vc.x * s_re[l]     - vc.y * s_im[l]
                 + vc.z * s_re[8 + l] - vc.w * s_im[8 + l];
        float pi = vc.x * s_im[l]     + vc.y * s_re[l]
                 + vc.z * s_im[8 + l] + vc.w * s_re[8 + l];
        o_re[gq] += __shfl_xor(pr, 1, 64);
        o_im[gq] += __shfl_xor(pi, 1, 64);
      }
    }
  }

  // ---- k = 1..3: fully local to the half (bits [3:0] of g) ----
#pragma unroll
  for (int k = 1; k < 4; k++) {
    const int sh = 3 - k;  // 2, 1, 0
    const float* ub = &ul[(k * 16 + b) * USTRIDE];
#pragma unroll
    for (int i = 0; i < 4; i++) {
      const float4 v0 = *(const float4*)(ub + i * 8);      // j=0,1
      const float4 v1 = *(const float4*)(ub + i * 8 + 4);  // j=2,3
#pragma unroll
      for (int qq = 0; qq < 4; qq++) {
        const int low  = qq & ((1 << sh) - 1);
        const int high = (qq >> sh) << (sh + 2);
        const int gb   = high | low;           // gq with pair bits cleared
        const int gq   = gb | (i << sh);
        const int s0 = gb;
        const int s1 = gb | (1 << sh);
        const int s2 = gb | (2 << sh);
        const int s3 = gb | (3 << sh);
        o_re[gq] += v0.x * s_re[s0] - v0.y * s_im[s0]
                  + v0.z * s_re[s1] - v0.w * s_im[s1]
                  + v1.x * s_re[s2] - v1.y * s_im[s2]
                  + v1.z * s_re[s3] - v1.w * s_im[s3];
        o_im[gq] += v0.x * s_im[s0] + v0.y * s_re[s0]
                  + v0.z * s_im[s1] + v0.w * s_re[s1]
                  + v1.x * s_im[s2] + v1.y * s_re[s2]
                  + v1.z * s_im[s3] + v1.w * s_re[s3];
      }
    }
  }

#pragma unroll
  for (int q = 0; q < 16; q++) {
    const int off = col + ((gbase + q) << 19);
    __builtin_nontemporal_store(o_re[q], out + off);               // real
    __builtin_nontemporal_store(o_im[q], out + off + (1 << 24));   // imag
  }
}

extern "C" void kernel_launch(void* const* d_in, const int* in_sizes, int n_in,
                              void* d_out, int out_size, void* d_ws, size_t ws_size,
                              hipStream_t stream) {
  const float* Hre  = (const float*)d_in[0];
  const float* Him  = (const float*)d_in[1];
  const float* tevo = (const float*)d_in[2];
  const float* sre  = (const float*)d_in[3];
  const float* sim  = (const float*)d_in[4];
  float* out = (float*)d_out;
  float* uws = (float*)d_ws;  // UTOT floats = 9216 B

  compute_u_kernel<<<1, 256, 0, stream>>>(Hre, Him, tevo, uws);
  apply_gates_kernel<<<NCOL / 128, 256, 0, stream>>>(sre, sim, uws, out);
}

// Round 10
// 53.499 us; speedup vs baseline: 1.2890x; 1.2111x over previous
//
#include <hip/hip_runtime.h>

// Problem constants
#define NQ 20
#define DIMQ (1 << NQ)          // 2^20
#define NB 16                   // BATCH
#define NT 4                    // N_TERMS
#define RBITS 15                // low bits untouched by gates
#define NCOL (1 << (RBITS + 4)) // 2^15 r-values * 16 batches = 524288 columns

// U table layout in ws/LDS: per (k,b): 36 floats (16 complex interleaved + 4 pad)
//   base = (k*16 + b) * 36 ; entry (i,j): re at base + (i*4+j)*2, im at +1
//   36 floats = 144 B = 9*16 B -> every (k,b) base is 16B-aligned.
#define USTRIDE 36
#define UTOT (64 * USTRIDE)     // 2304 floats = 9216 B

// lane <-> lane^1 exchange as DPP quad_perm [1,0,3,2] (0xB1): pure VALU,
// no lgkmcnt wait, no ds-pipe traffic (vs __shfl_xor = ds_bpermute).
__device__ __forceinline__ float dpp_swap1(float x) {
  int xi = __builtin_bit_cast(int, x);
  int r  = __builtin_amdgcn_mov_dpp(xi, 0xB1, 0xF, 0xF, true);
  return __builtin_bit_cast(float, r);
}

// ---------------------------------------------------------------------------
// Kernel A: U[k,b] = exp(-i * H_k * t_{k,b}),  H_k = 0.5*(A + A^H), A = Hr + i Hi
// 256 threads: 64 tasks (k,b) x 4 rows. Scaling (2^-6) + 10-term Taylor + 6 squarings.
// ---------------------------------------------------------------------------
__global__ __launch_bounds__(256) void compute_u_kernel(
    const float* __restrict__ Hre, const float* __restrict__ Him,
    const float* __restrict__ tevo, float* __restrict__ uout) {
  __shared__ float er_s[64][4][4];
  __shared__ float ei_s[64][4][4];

  const int tid  = threadIdx.x;   // 0..255
  const int task = tid >> 2;      // 0..63
  const int row  = tid & 3;       // 0..3
  const int k    = task >> 4;     // 0..3
  const int b    = task & 15;     // 0..15

  float Ar[4][4], Ai[4][4];
#pragma unroll
  for (int i = 0; i < 4; i++) {
#pragma unroll
    for (int j = 0; j < 4; j++) {
      Ar[i][j] = Hre[k * 16 + i * 4 + j];
      Ai[i][j] = Him[k * 16 + i * 4 + j];
    }
  }
  const float t = tevo[k * NB + b];
  const float ts = t * (1.0f / 64.0f);  // scale 2^-6 folded in

  // G = -i * H * ts ; H = 0.5*(A + A^H)
  float Gr[4][4], Gi[4][4];
#pragma unroll
  for (int i = 0; i < 4; i++) {
#pragma unroll
    for (int j = 0; j < 4; j++) {
      const float hr = 0.5f * (Ar[i][j] + Ar[j][i]);
      const float hi = 0.5f * (Ai[i][j] - Ai[j][i]);
      Gr[i][j] = ts * hi;
      Gi[i][j] = -ts * hr;
    }
  }

  // Taylor: E = I + sum_{m=1..10} G^m/m!   (row `row` only; full G in regs)
  float Er[4], Ei[4], Tr[4], Ti[4];
#pragma unroll
  for (int j = 0; j < 4; j++) {
    Er[j] = (j == row) ? 1.0f : 0.0f;
    Ei[j] = 0.0f;
    Tr[j] = Er[j];
    Ti[j] = 0.0f;
  }
#pragma unroll
  for (int m = 1; m <= 10; m++) {
    const float inv = 1.0f / (float)m;
    float nr[4], ni[4];
#pragma unroll
    for (int j = 0; j < 4; j++) {
      float ar = 0.0f, ai = 0.0f;
#pragma unroll
      for (int p = 0; p < 4; p++) {
        ar += Tr[p] * Gr[p][j] - Ti[p] * Gi[p][j];
        ai += Tr[p] * Gi[p][j] + Ti[p] * Gr[p][j];
      }
      nr[j] = ar * inv;
      ni[j] = ai * inv;
    }
#pragma unroll
    for (int j = 0; j < 4; j++) {
      Tr[j] = nr[j]; Ti[j] = ni[j];
      Er[j] += nr[j]; Ei[j] += ni[j];
    }
  }

  // 6 squarings via LDS (uniform trip count -> barriers are safe)
  for (int q = 0; q < 6; q++) {
    __syncthreads();
#pragma unroll
    for (int j = 0; j < 4; j++) {
      er_s[task][row][j] = Er[j];
      ei_s[task][row][j] = Ei[j];
    }
    __syncthreads();
    float nr[4], ni[4];
#pragma unroll
    for (int j = 0; j < 4; j++) {
      float ar = 0.0f, ai = 0.0f;
#pragma unroll
      for (int p = 0; p < 4; p++) {
        ar += Er[p] * er_s[task][p][j] - Ei[p] * ei_s[task][p][j];
        ai += Er[p] * ei_s[task][p][j] + Ei[p] * er_s[task][p][j];
      }
      nr[j] = ar; ni[j] = ai;
    }
#pragma unroll
    for (int j = 0; j < 4; j++) { Er[j] = nr[j]; Ei[j] = ni[j]; }
  }

  // Store U rows: layout [k][b][16 complex interleaved], row stride 36 floats
  const int ubase = (k * 16 + b) * USTRIDE;
#pragma unroll
  for (int j = 0; j < 4; j++) {
    uout[ubase + (row * 4 + j) * 2]     = Er[j];
    uout[ubase + (row * 4 + j) * 2 + 1] = Ei[j];
  }
}

// ---------------------------------------------------------------------------
// Kernel B (r5 structure verbatim, shfl -> DPP): two ADJACENT LANES per
// column (r,b); each owns one 16-g half.
//   half = tid&1, col = blockIdx*128 + (tid>>1), b = (tid>>1)&15.
// Gates k=1..3 act inside a half (g bits [3:0]). Gate k=0 (g bits [4:3])
// crosses halves: each thread computes its own-source partial for the
// partner's outputs and exchanges it with a DPP quad_perm lane^1 swap.
// ---------------------------------------------------------------------------
__global__ __launch_bounds__(256, 4) void apply_gates_kernel(
    const float* __restrict__ sre, const float* __restrict__ sim,
    const float* __restrict__ u, float* __restrict__ out) {
  __shared__ __align__(16) float ul[UTOT];
  const int tid = threadIdx.x;
  // stage U table (9 KiB) to LDS; UTOT = 9*256 exactly
#pragma unroll
  for (int q = 0; q < 9; q++) ul[tid + q * 256] = u[tid + q * 256];
  __syncthreads();

  const int half  = tid & 1;                      // wave lanes alternate halves
  const int col   = blockIdx.x * 128 + (tid >> 1);  // r*16 + b
  const int b     = (tid >> 1) & 15;
  const int gbase = half << 4;

  // own half: 16 complex
  float s_re[16], s_im[16];
#pragma unroll
  for (int q = 0; q < 16; q++) {
    const int off = col + ((gbase + q) << 19);
    s_re[q] = sre[off];
    s_im[q] = sim[off];
  }

  float o_re[16], o_im[16];

  // ---- k = 0 (g bits [4:3]) : own term + DPP-exchanged cross term ----
  // own output g = half<<4 | b3<<3 | l : row i = 2*half + b3.
  // own sources s_re[l] (j=2*half), s_re[8+l] (j=2*half+1).
  // cross partial: contribution of MY sources (same j) to partner output
  // with row i' = 2*(half^1) + b3; partner adds the swapped value.
  {
    const float* ub0 = &ul[b * USTRIDE];  // k = 0 block
    const int h4 = half * 4;              // float offset of (j=2h) entry pair
#pragma unroll
    for (int b3 = 0; b3 < 2; b3++) {
      const float4 vo = *(const float4*)(ub0 + (half * 2 + b3) * 8 + h4);
      const float4 vc = *(const float4*)(ub0 + ((half ^ 1) * 2 + b3) * 8 + h4);
#pragma unroll
      for (int l = 0; l < 8; l++) {
        const int gq = b3 * 8 + l;
        o_re[gq] = vo.x * s_re[l]     - vo.y * s_im[l]
                 + vo.z * s_re[8 + l] - vo.w * s_im[8 + l];
        o_im[gq] = vo.x * s_im[l]     + vo.y * s_re[l]
                 + vo.z * s_im[8 + l] + vo.w * s_re[8 + l];
        float pr = vc.x * s_re[l]     - vc.y * s_im[l]
                 + vc.z * s_re[8 + l] - vc.w * s_im[8 + l];
        float pi = vc.x * s_im[l]     + vc.y * s_re[l]
                 + vc.z * s_im[8 + l] + vc.w * s_re[8 + l];
        o_re[gq] += dpp_swap1(pr);
        o_im[gq] += dpp_swap1(pi);
      }
    }
  }

  // ---- k = 1..3: fully local to the half (bits [3:0] of g) ----
#pragma unroll
  for (int k = 1; k < 4; k++) {
    const int sh = 3 - k;  // 2, 1, 0
    const float* ub = &ul[(k * 16 + b) * USTRIDE];
#pragma unroll
    for (int i = 0; i < 4; i++) {
      const float4 v0 = *(const float4*)(ub + i * 8);      // j=0,1
      const float4 v1 = *(const float4*)(ub + i * 8 + 4);  // j=2,3
#pragma unroll
      for (int qq = 0; qq < 4; qq++) {
        const int low  = qq & ((1 << sh) - 1);
        const int high = (qq >> sh) << (sh + 2);
        const int gb   = high | low;           // gq with pair bits cleared
        const int gq   = gb | (i << sh);
        const int s0 = gb;
        const int s1 = gb | (1 << sh);
        const int s2 = gb | (2 << sh);
        const int s3 = gb | (3 << sh);
        o_re[gq] += v0.x * s_re[s0] - v0.y * s_im[s0]
                  + v0.z * s_re[s1] - v0.w * s_im[s1]
                  + v1.x * s_re[s2] - v1.y * s_im[s2]
                  + v1.z * s_re[s3] - v1.w * s_im[s3];
        o_im[gq] += v0.x * s_im[s0] + v0.y * s_re[s0]
                  + v0.z * s_im[s1] + v0.w * s_re[s1]
                  + v1.x * s_im[s2] + v1.y * s_re[s2]
                  + v1.z * s_im[s3] + v1.w * s_re[s3];
      }
    }
  }

#pragma unroll
  for (int q = 0; q < 16; q++) {
    const int off = col + ((gbase + q) << 19);
    __builtin_nontemporal_store(o_re[q], out + off);               // real
    __builtin_nontemporal_store(o_im[q], out + off + (1 << 24));   // imag
  }
}

extern "C" void kernel_launch(void* const* d_in, const int* in_sizes, int n_in,
                              void* d_out, int out_size, void* d_ws, size_t ws_size,
                              hipStream_t stream) {
  const float* Hre  = (const float*)d_in[0];
  const float* Him  = (const float*)d_in[1];
  const float* tevo = (const float*)d_in[2];
  const float* sre  = (const float*)d_in[3];
  const float* sim  = (const float*)d_in[4];
  float* out = (float*)d_out;
  float* uws = (float*)d_ws;  // UTOT floats = 9216 B

  compute_u_kernel<<<1, 256, 0, stream>>>(Hre, Him, tevo, uws);
  apply_gates_kernel<<<NCOL / 128, 256, 0, stream>>>(sre, sim, uws, out);
}